// Round 3
// baseline (127.553 us; speedup 1.0000x reference)
//
#include <hip/hip_runtime.h>

#define BB 4
#define TT 4096
#define CUT 2048
#define CE 1024
#define HD 64
#define QSC 0.045084220027780106f   // 1024^-0.5 * log2(e)

typedef unsigned short u16;
typedef unsigned int u32;
typedef __attribute__((ext_vector_type(8))) short bf16x8;
typedef __attribute__((ext_vector_type(4))) float f32x4;

__device__ __forceinline__ u16 f2b(float f) {
  union { float f; unsigned u; } v; v.f = f;
  unsigned r = v.u + 0x7fffu + ((v.u >> 16) & 1u);   // RNE to bf16
  return (u16)(r >> 16);
}

__device__ __forceinline__ u32 cvtpk(float lo, float hi) {
  u32 r;
  asm("v_cvt_pk_bf16_f32 %0, %1, %2" : "=v"(r) : "v"(lo), "v"(hi));
  return r;
}

// ---- Kernel 1: W3T[(m*64+n)*1024 + k] = bf16(W_m[k][n]),  m: 0=K,1=V,2=Q ----
__global__ void wtrans_k(const float* __restrict__ Wk, const float* __restrict__ Wv,
                         const float* __restrict__ Wq, u16* __restrict__ w3t) {
  int id = blockIdx.x * 256 + threadIdx.x;     // 196608 total
  int k = id & 1023;
  int n = (id >> 10) & 63;
  int m = id >> 16;
  const float* W = (m == 0) ? Wk : (m == 1) ? Wv : Wq;
  w3t[id] = f2b(W[k * 64 + n]);
}

// ---- Kernel 2: QKV projection. 16 waves: 4 row-groups x 4 K-splits. ----
// No LDS staging of W (read L2-resident w3t directly); barrier-free main loop.
__launch_bounds__(1024, 4)
__global__ void proj_k(const float* __restrict__ x, const u16* __restrict__ w3t,
                       const float* __restrict__ bk, const float* __restrict__ bv,
                       const float* __restrict__ bq,
                       u16* __restrict__ Kb, u16* __restrict__ Vb, u16* __restrict__ Qb) {
  __shared__ f32x4 cl[2][4][3][4][64];          // [pair][rg][m][nt][lane]  96KB
  const int tid  = threadIdx.x;
  const int lane = tid & 63;
  const int wv   = tid >> 6;                    // 0..15
  const int rg   = wv & 3;                      // row-group
  const int kh   = wv >> 2;                     // K-split 0..3
  const int l15  = lane & 15;
  const int g    = lane >> 4;
  const int row  = blockIdx.x * 64 + rg * 16 + l15;
  const float* xrow = x + (size_t)row * CE + kh * 256;
  const u16*   wb   = w3t + kh * 256;

  f32x4 acc[3][4];
  #pragma unroll
  for (int m = 0; m < 3; ++m)
    #pragma unroll
    for (int nt = 0; nt < 4; ++nt) acc[m][nt] = (f32x4){0.f, 0.f, 0.f, 0.f};

  #pragma unroll
  for (int kb = 0; kb < 4; ++kb) {
    #pragma unroll
    for (int kc = 0; kc < 2; ++kc) {
      const int ko = kb * 64 + kc * 32 + g * 8;
      const float* xp = xrow + ko;
      f32x4 xa = *(const f32x4*)xp;
      f32x4 xb = *(const f32x4*)(xp + 4);
      bf16x8 a;
      #pragma unroll
      for (int j = 0; j < 4; ++j) { a[j] = (short)f2b(xa[j]); a[j + 4] = (short)f2b(xb[j]); }
      #pragma unroll
      for (int m = 0; m < 3; ++m)
        #pragma unroll
        for (int nt = 0; nt < 4; ++nt) {
          bf16x8 bfr = *(const bf16x8*)&wb[(size_t)(m * 64 + nt * 16 + l15) * 1024 + ko];
          acc[m][nt] = __builtin_amdgcn_mfma_f32_16x16x32_bf16(a, bfr, acc[m][nt], 0, 0, 0);
        }
    }
  }

  // ---- K-split combine: (0+=2, 1+=3), then (0+=1), in LDS ----
  if (kh >= 2) {
    #pragma unroll
    for (int m = 0; m < 3; ++m)
      #pragma unroll
      for (int nt = 0; nt < 4; ++nt) cl[kh - 2][rg][m][nt][lane] = acc[m][nt];
  }
  __syncthreads();
  if (kh < 2) {
    #pragma unroll
    for (int m = 0; m < 3; ++m)
      #pragma unroll
      for (int nt = 0; nt < 4; ++nt) acc[m][nt] += cl[kh][rg][m][nt][lane];
  }
  __syncthreads();
  if (kh == 1) {
    #pragma unroll
    for (int m = 0; m < 3; ++m)
      #pragma unroll
      for (int nt = 0; nt < 4; ++nt) cl[0][rg][m][nt][lane] = acc[m][nt];
  }
  __syncthreads();
  if (kh == 0) {
    #pragma unroll
    for (int m = 0; m < 3; ++m)
      #pragma unroll
      for (int nt = 0; nt < 4; ++nt) acc[m][nt] += cl[0][rg][m][nt][lane];

    const int orow0 = blockIdx.x * 64 + rg * 16 + g * 4;   // C/D: row=(lane>>4)*4+r
    #pragma unroll
    for (int m = 0; m < 3; ++m) {
      const float* bias = (m == 0) ? bk : (m == 1) ? bv : bq;
      #pragma unroll
      for (int nt = 0; nt < 4; ++nt) {
        int col = nt * 16 + l15;
        float bc = bias[col];
        #pragma unroll
        for (int r = 0; r < 4; ++r) {
          int orow = orow0 + r;
          float val = acc[m][nt][r] + bc;
          if (m == 0)      Kb[(size_t)orow * HD + col] = f2b(val);
          else if (m == 1) Vb[(size_t)orow * HD + col] = f2b(val);
          else {
            int t = orow & (TT - 1);
            if (t >= CUT)  // Q pre-scaled by 1024^-0.5 * log2(e) for exp2 softmax
              Qb[((size_t)(orow >> 12) * CUT + (t - CUT)) * HD + col] = f2b(val * QSC);
          }
        }
      }
    }
  }
}

// ---- Kernel 2b: VT[b][d][t] = Vb[b][t][d]  (bf16 global transpose, L2-resident) ----
__global__ void vtrans_k(const u16* __restrict__ Vb, u16* __restrict__ VTg) {
  int id = blockIdx.x * 256 + threadIdx.x;     // 131072 total
  int t8 = id & 511;                           // 8-token group
  int d  = (id >> 9) & 63;
  int b  = id >> 15;
  const u16* src = Vb + ((size_t)b * TT + t8 * 8) * HD + d;
  bf16x8 vv;
  #pragma unroll
  for (int j = 0; j < 8; ++j) vv[j] = (short)src[j * HD];
  *(bf16x8*)&VTg[((size_t)b * HD + d) * TT + t8 * 8] = vv;
}

// ---- Kernel 3: attention, swapped-QK, FIXED-MAX softmax (m=0), 8-way KV-split ----
// No per-chunk reductions/broadcasts; unnormalized O + in-lane l-sum; sum-combine.
__launch_bounds__(512, 4)
__global__ void attn_k(const u16* __restrict__ Qb, const u16* __restrict__ Kb,
                       const u16* __restrict__ VTg, float* __restrict__ out) {
  __shared__ u32   PLd[8][16][36];              // per-wave P (bf16 pairs): [q][key/2]
  __shared__ float OO[8][16][66];               // per-wave unnormalized O: [q][d]
  __shared__ float OL[8][16];                   // per-wave l-sum per q
  const int tid  = threadIdx.x;
  const int lane = tid & 63;
  const int wv   = tid >> 6;
  const int l15  = lane & 15;
  const int g    = lane >> 4;
  // XCD-aware swizzle: 64 consecutive logical tiles per XCD (same-batch K/V locality)
  const int id   = blockIdx.x;                  // 0..511
  const int f    = (id & 7) * 64 + (id >> 3);
  const int i0   = (f & 127) * 16;
  const int b    = f >> 7;

  const int qabs = CUT + i0 + l15;              // abs pos of this lane's q column (S^T)
  const int qmin = CUT + i0;

  const u16* qrow = Qb + ((size_t)b * CUT + i0 + l15) * HD;
  bf16x8 qf0 = *(const bf16x8*)&qrow[g * 8];
  bf16x8 qf1 = *(const bf16x8*)&qrow[32 + g * 8];

  f32x4 o[4];
  #pragma unroll
  for (int dt = 0; dt < 4; ++dt) o[dt] = (f32x4){0.f, 0.f, 0.f, 0.f};
  float lsum = 0.f;

  const int kv_end = CUT + i0 + 16;
  const int nch = (kv_end + 63) >> 6;           // 33..64 chunks
  const u16* Kbase = Kb + (size_t)b * TT * HD;
  const u16* Vbase = VTg + (size_t)b * HD * TT;

  for (int c = wv; c < nch; c += 8) {
    const int kv0 = c << 6;

    f32x4 st[4];                                // S^T: lane holds q=l15, key=g*4+r
    #pragma unroll
    for (int kt = 0; kt < 4; ++kt) {
      const u16* krow = Kbase + (size_t)(kv0 + kt * 16 + l15) * HD;
      bf16x8 kf0 = *(const bf16x8*)&krow[g * 8];
      bf16x8 kf1 = *(const bf16x8*)&krow[32 + g * 8];
      f32x4 s = (f32x4){0.f, 0.f, 0.f, 0.f};
      s = __builtin_amdgcn_mfma_f32_16x16x32_bf16(kf0, qf0, s, 0, 0, 0);
      s = __builtin_amdgcn_mfma_f32_16x16x32_bf16(kf1, qf1, s, 0, 0, 0);
      st[kt] = s;
    }

    // p = 2^s  (scale*log2e folded into Q; |s| < 6 so no overflow; fixed max)
    if (kv0 + 63 <= qmin) {                     // wave-uniform: fully unmasked chunk
      #pragma unroll
      for (int kt = 0; kt < 4; ++kt)
        #pragma unroll
        for (int r = 0; r < 4; ++r) {
          float p = exp2f(st[kt][r]);
          st[kt][r] = p;
          lsum += p;
        }
    } else {
      #pragma unroll
      for (int kt = 0; kt < 4; ++kt)
        #pragma unroll
        for (int r = 0; r < 4; ++r) {
          int key = kv0 + kt * 16 + g * 4 + r;
          float p = exp2f(st[kt][r]);
          p = (key <= qabs) ? p : 0.f;
          st[kt][r] = p;
          lsum += p;
        }
    }

    #pragma unroll
    for (int kt = 0; kt < 4; ++kt) {            // pack P->bf16, wave-private LDS
      u32 d0 = cvtpk(st[kt][0], st[kt][1]);
      u32 d1 = cvtpk(st[kt][2], st[kt][3]);
      u32* p = &PLd[wv][l15][kt * 8 + g * 2];
      p[0] = d0; p[1] = d1;
    }

    #pragma unroll
    for (int c2 = 0; c2 < 2; ++c2) {            // O += P @ V  (V^T frags from L2)
      bf16x8 pa = *(const bf16x8*)&PLd[wv][l15][c2 * 16 + g * 4];
      #pragma unroll
      for (int dt = 0; dt < 4; ++dt) {
        bf16x8 vf = *(const bf16x8*)&Vbase[(size_t)(dt * 16 + l15) * TT + kv0 + c2 * 32 + g * 8];
        o[dt] = __builtin_amdgcn_mfma_f32_16x16x32_bf16(pa, vf, o[dt], 0, 0, 0);
      }
    }
  }

  // ---- l reduce over g-groups (only 2 shuffles, once per wave) ----
  lsum += __shfl_xor(lsum, 16);
  lsum += __shfl_xor(lsum, 32);
  if (lane < 16) OL[wv][l15] = lsum;
  #pragma unroll
  for (int dt = 0; dt < 4; ++dt)
    #pragma unroll
    for (int r = 0; r < 4; ++r)
      OO[wv][g * 4 + r][dt * 16 + l15] = o[dt][r];
  __syncthreads();

  // ---- combine across the 8 KV-split waves: pure sums, then normalize ----
  #pragma unroll
  for (int e = tid; e < 1024; e += 512) {
    int q = e >> 6, d = e & 63;
    float L = 0.f, O = 0.f;
    #pragma unroll
    for (int w = 0; w < 8; ++w) { L += OL[w][q]; O += OO[w][q][d]; }
    out[((size_t)b * CUT + i0 + q) * HD + d] = O / L;
  }
}

extern "C" void kernel_launch(void* const* d_in, const int* in_sizes, int n_in,
                              void* d_out, int out_size, void* d_ws, size_t ws_size,
                              hipStream_t stream) {
  const float* x  = (const float*)d_in[0];
  const float* Wq = (const float*)d_in[1];
  const float* bq = (const float*)d_in[2];
  const float* Wk = (const float*)d_in[3];
  const float* bk = (const float*)d_in[4];
  const float* Wv = (const float*)d_in[5];
  const float* bv = (const float*)d_in[6];
  float* out = (float*)d_out;

  u16* Kb  = (u16*)d_ws;                               // [B*T*64]   bf16
  u16* Vb  = Kb + (size_t)BB * TT * HD;                // [B*T*64]
  u16* Qb  = Vb + (size_t)BB * TT * HD;                // [B*CUT*64] (pre-scaled)
  u16* W3T = Qb + (size_t)BB * CUT * HD;               // [192*1024]
  u16* VTg = W3T + (size_t)192 * 1024;                 // [B*64*T]   V transposed

  wtrans_k<<<768, 256, 0, stream>>>(Wk, Wv, Wq, W3T);
  proj_k<<<256, 1024, 0, stream>>>(x, W3T, bk, bv, bq, Kb, Vb, Qb);
  vtrans_k<<<512, 256, 0, stream>>>(Vb, VTg);
  attn_k<<<512, 512, 0, stream>>>(Qb, Kb, VTg, out);
}

// Round 4
// 98.921 us; speedup vs baseline: 1.2894x; 1.2894x over previous
//
#include <hip/hip_runtime.h>

#define BB 4
#define TT 4096
#define CUT 2048
#define CE 1024
#define HD 64
#define QSC 0.045084220027780106f   // 1024^-0.5 * log2(e)

typedef unsigned short u16;
typedef unsigned int u32;
typedef __attribute__((ext_vector_type(8))) short bf16x8;
typedef __attribute__((ext_vector_type(4))) float f32x4;

__device__ __forceinline__ u16 f2b(float f) {
  union { float f; unsigned u; } v; v.f = f;
  unsigned r = v.u + 0x7fffu + ((v.u >> 16) & 1u);   // RNE to bf16
  return (u16)(r >> 16);
}

__device__ __forceinline__ u32 cvtpk(float lo, float hi) {
  u32 r;
  asm("v_cvt_pk_bf16_f32 %0, %1, %2" : "=v"(r) : "v"(lo), "v"(hi));
  return r;
}

// ---- Kernel 1: W3F = W in MFMA B-fragment order. ----
// frag id f = mnt*32 + kstep  (mnt = m*4+nt, m: 0=K,1=V,2=Q).
// W3F[f*512 + lane*8 + j] = W_m[k*64 + col],  k = kstep*32 + (lane>>4)*8 + j,
//                                             col = nt*16 + (lane&15).
// A wave's B-frag load is then ONE contiguous 1KB global_load_dwordx4.
__global__ void wtrans_k(const float* __restrict__ Wk, const float* __restrict__ Wv,
                         const float* __restrict__ Wq, u16* __restrict__ w3f) {
  int id = blockIdx.x * 256 + threadIdx.x;     // 196608 total
  int j    = id & 7;
  int lane = (id >> 3) & 63;
  int f    = id >> 9;                          // 0..383
  int kstep = f & 31;
  int mnt   = f >> 5;
  int m  = mnt >> 2;
  int nt = mnt & 3;
  int k   = kstep * 32 + (lane >> 4) * 8 + j;
  int col = nt * 16 + (lane & 15);
  const float* W = (m == 0) ? Wk : (m == 1) ? Wv : Wq;
  w3f[id] = f2b(W[k * 64 + col]);
}

// ---- Kernel 2: QKV projection. Block = 4 waves = 4 K-splits of one 32-row tile.
// B-frags: contiguous 1KB loads from L2-resident W3F (no LDS staging, no barriers
// in main loop). Each B-frag reused by 2 A-frag row-halves.
__launch_bounds__(256, 2)
__global__ void proj_k(const float* __restrict__ x, const u16* __restrict__ w3f,
                       const float* __restrict__ bk, const float* __restrict__ bv,
                       const float* __restrict__ bq,
                       u16* __restrict__ Kb, u16* __restrict__ Vb, u16* __restrict__ Qb) {
  __shared__ f32x4 cl[2][2][12][64];            // 48KB combine buffer
  const int tid  = threadIdx.x;
  const int lane = tid & 63;
  const int kh   = tid >> 6;                    // wave = K-split 0..3
  const int l15  = lane & 15;
  const int g    = lane >> 4;
  const int r0   = blockIdx.x * 32;

  f32x4 acc[2][12];
  #pragma unroll
  for (int h = 0; h < 2; ++h)
    #pragma unroll
    for (int t = 0; t < 12; ++t) acc[h][t] = (f32x4){0.f, 0.f, 0.f, 0.f};

  const float* x0 = x + (size_t)(r0 + l15) * CE;
  const float* x1 = x + (size_t)(r0 + 16 + l15) * CE;

  #pragma unroll
  for (int kc = 0; kc < 8; ++kc) {
    const int ko = kh * 256 + kc * 32 + g * 8;
    bf16x8 a0, a1;
    {
      f32x4 xa = *(const f32x4*)(x0 + ko);
      f32x4 xb = *(const f32x4*)(x0 + ko + 4);
      f32x4 ya = *(const f32x4*)(x1 + ko);
      f32x4 yb = *(const f32x4*)(x1 + ko + 4);
      #pragma unroll
      for (int j = 0; j < 4; ++j) {
        a0[j] = (short)f2b(xa[j]); a0[j + 4] = (short)f2b(xb[j]);
        a1[j] = (short)f2b(ya[j]); a1[j + 4] = (short)f2b(yb[j]);
      }
    }
    const int kstep = kh * 8 + kc;
    #pragma unroll
    for (int mnt = 0; mnt < 12; ++mnt) {
      bf16x8 bfr = *(const bf16x8*)&w3f[(size_t)(mnt * 32 + kstep) * 512 + lane * 8];
      acc[0][mnt] = __builtin_amdgcn_mfma_f32_16x16x32_bf16(a0, bfr, acc[0][mnt], 0, 0, 0);
      acc[1][mnt] = __builtin_amdgcn_mfma_f32_16x16x32_bf16(a1, bfr, acc[1][mnt], 0, 0, 0);
    }
  }

  // ---- K-split tree combine in LDS: (0+=2, 1+=3), then (0+=1) ----
  if (kh >= 2) {
    #pragma unroll
    for (int h = 0; h < 2; ++h)
      #pragma unroll
      for (int t = 0; t < 12; ++t) cl[kh - 2][h][t][lane] = acc[h][t];
  }
  __syncthreads();
  if (kh < 2) {
    #pragma unroll
    for (int h = 0; h < 2; ++h)
      #pragma unroll
      for (int t = 0; t < 12; ++t) acc[h][t] += cl[kh][h][t][lane];
  }
  __syncthreads();
  if (kh == 1) {
    #pragma unroll
    for (int h = 0; h < 2; ++h)
      #pragma unroll
      for (int t = 0; t < 12; ++t) cl[0][h][t][lane] = acc[h][t];
  }
  __syncthreads();
  if (kh == 0) {
    #pragma unroll
    for (int h = 0; h < 2; ++h)
      #pragma unroll
      for (int t = 0; t < 12; ++t) acc[h][t] += cl[0][h][t][lane];

    #pragma unroll
    for (int h = 0; h < 2; ++h) {
      const int orow0 = r0 + h * 16 + g * 4;    // C/D: row=(lane>>4)*4+r, col=l15
      #pragma unroll
      for (int m = 0; m < 3; ++m) {
        const float* bias = (m == 0) ? bk : (m == 1) ? bv : bq;
        #pragma unroll
        for (int nt = 0; nt < 4; ++nt) {
          int col = nt * 16 + l15;
          float bc = bias[col];
          #pragma unroll
          for (int r = 0; r < 4; ++r) {
            int orow = orow0 + r;
            float val = acc[h][m * 4 + nt][r] + bc;
            if (m == 0)      Kb[(size_t)orow * HD + col] = f2b(val);
            else if (m == 1) Vb[(size_t)orow * HD + col] = f2b(val);
            else {
              int t = orow & (TT - 1);
              if (t >= CUT)  // Q pre-scaled by 1024^-0.5 * log2(e) for exp2 softmax
                Qb[((size_t)(orow >> 12) * CUT + (t - CUT)) * HD + col] = f2b(val * QSC);
            }
          }
        }
      }
    }
  }
}

// ---- Kernel 2b: VT[b][d][t] = Vb[b][t][d]  (bf16 global transpose, L2-resident) ----
__global__ void vtrans_k(const u16* __restrict__ Vb, u16* __restrict__ VTg) {
  int id = blockIdx.x * 256 + threadIdx.x;     // 131072 total
  int t8 = id & 511;                           // 8-token group
  int d  = (id >> 9) & 63;
  int b  = id >> 15;
  const u16* src = Vb + ((size_t)b * TT + t8 * 8) * HD + d;
  bf16x8 vv;
  #pragma unroll
  for (int j = 0; j < 8; ++j) vv[j] = (short)src[j * HD];
  *(bf16x8*)&VTg[((size_t)b * HD + d) * TT + t8 * 8] = vv;
}

// ---- Kernel 3: attention, swapped-QK, FIXED-MAX softmax (m=0), 8-way KV-split ----
// (unchanged from round 3 — left identical for clean attribution)
__launch_bounds__(512, 4)
__global__ void attn_k(const u16* __restrict__ Qb, const u16* __restrict__ Kb,
                       const u16* __restrict__ VTg, float* __restrict__ out) {
  __shared__ u32   PLd[8][16][36];              // per-wave P (bf16 pairs): [q][key/2]
  __shared__ float OO[8][16][66];               // per-wave unnormalized O: [q][d]
  __shared__ float OL[8][16];                   // per-wave l-sum per q
  const int tid  = threadIdx.x;
  const int lane = tid & 63;
  const int wv   = tid >> 6;
  const int l15  = lane & 15;
  const int g    = lane >> 4;
  const int id   = blockIdx.x;                  // 0..511
  const int f    = (id & 7) * 64 + (id >> 3);   // XCD-aware swizzle
  const int i0   = (f & 127) * 16;
  const int b    = f >> 7;

  const int qabs = CUT + i0 + l15;              // abs pos of this lane's q column (S^T)
  const int qmin = CUT + i0;

  const u16* qrow = Qb + ((size_t)b * CUT + i0 + l15) * HD;
  bf16x8 qf0 = *(const bf16x8*)&qrow[g * 8];
  bf16x8 qf1 = *(const bf16x8*)&qrow[32 + g * 8];

  f32x4 o[4];
  #pragma unroll
  for (int dt = 0; dt < 4; ++dt) o[dt] = (f32x4){0.f, 0.f, 0.f, 0.f};
  float lsum = 0.f;

  const int kv_end = CUT + i0 + 16;
  const int nch = (kv_end + 63) >> 6;           // 33..64 chunks
  const u16* Kbase = Kb + (size_t)b * TT * HD;
  const u16* Vbase = VTg + (size_t)b * HD * TT;

  for (int c = wv; c < nch; c += 8) {
    const int kv0 = c << 6;

    f32x4 st[4];                                // S^T: lane holds q=l15, key=g*4+r
    #pragma unroll
    for (int kt = 0; kt < 4; ++kt) {
      const u16* krow = Kbase + (size_t)(kv0 + kt * 16 + l15) * HD;
      bf16x8 kf0 = *(const bf16x8*)&krow[g * 8];
      bf16x8 kf1 = *(const bf16x8*)&krow[32 + g * 8];
      f32x4 s = (f32x4){0.f, 0.f, 0.f, 0.f};
      s = __builtin_amdgcn_mfma_f32_16x16x32_bf16(kf0, qf0, s, 0, 0, 0);
      s = __builtin_amdgcn_mfma_f32_16x16x32_bf16(kf1, qf1, s, 0, 0, 0);
      st[kt] = s;
    }

    // p = 2^s  (scale*log2e folded into Q; |s| < 6 so no overflow; fixed max)
    if (kv0 + 63 <= qmin) {                     // wave-uniform: fully unmasked chunk
      #pragma unroll
      for (int kt = 0; kt < 4; ++kt)
        #pragma unroll
        for (int r = 0; r < 4; ++r) {
          float p = exp2f(st[kt][r]);
          st[kt][r] = p;
          lsum += p;
        }
    } else {
      #pragma unroll
      for (int kt = 0; kt < 4; ++kt)
        #pragma unroll
        for (int r = 0; r < 4; ++r) {
          int key = kv0 + kt * 16 + g * 4 + r;
          float p = exp2f(st[kt][r]);
          p = (key <= qabs) ? p : 0.f;
          st[kt][r] = p;
          lsum += p;
        }
    }

    #pragma unroll
    for (int kt = 0; kt < 4; ++kt) {            // pack P->bf16, wave-private LDS
      u32 d0 = cvtpk(st[kt][0], st[kt][1]);
      u32 d1 = cvtpk(st[kt][2], st[kt][3]);
      u32* p = &PLd[wv][l15][kt * 8 + g * 2];
      p[0] = d0; p[1] = d1;
    }

    #pragma unroll
    for (int c2 = 0; c2 < 2; ++c2) {            // O += P @ V  (V^T frags from L2)
      bf16x8 pa = *(const bf16x8*)&PLd[wv][l15][c2 * 16 + g * 4];
      #pragma unroll
      for (int dt = 0; dt < 4; ++dt) {
        bf16x8 vf = *(const bf16x8*)&Vbase[(size_t)(dt * 16 + l15) * TT + kv0 + c2 * 32 + g * 8];
        o[dt] = __builtin_amdgcn_mfma_f32_16x16x32_bf16(pa, vf, o[dt], 0, 0, 0);
      }
    }
  }

  // ---- l reduce over g-groups (only 2 shuffles, once per wave) ----
  lsum += __shfl_xor(lsum, 16);
  lsum += __shfl_xor(lsum, 32);
  if (lane < 16) OL[wv][l15] = lsum;
  #pragma unroll
  for (int dt = 0; dt < 4; ++dt)
    #pragma unroll
    for (int r = 0; r < 4; ++r)
      OO[wv][g * 4 + r][dt * 16 + l15] = o[dt][r];
  __syncthreads();

  // ---- combine across the 8 KV-split waves: pure sums, then normalize ----
  #pragma unroll
  for (int e = tid; e < 1024; e += 512) {
    int q = e >> 6, d = e & 63;
    float L = 0.f, O = 0.f;
    #pragma unroll
    for (int w = 0; w < 8; ++w) { L += OL[w][q]; O += OO[w][q][d]; }
    out[((size_t)b * CUT + i0 + q) * HD + d] = O / L;
  }
}

extern "C" void kernel_launch(void* const* d_in, const int* in_sizes, int n_in,
                              void* d_out, int out_size, void* d_ws, size_t ws_size,
                              hipStream_t stream) {
  const float* x  = (const float*)d_in[0];
  const float* Wq = (const float*)d_in[1];
  const float* bq = (const float*)d_in[2];
  const float* Wk = (const float*)d_in[3];
  const float* bk = (const float*)d_in[4];
  const float* Wv = (const float*)d_in[5];
  const float* bv = (const float*)d_in[6];
  float* out = (float*)d_out;

  u16* Kb  = (u16*)d_ws;                               // [B*T*64]   bf16
  u16* Vb  = Kb + (size_t)BB * TT * HD;                // [B*T*64]
  u16* Qb  = Vb + (size_t)BB * TT * HD;                // [B*CUT*64] (pre-scaled)
  u16* W3F = Qb + (size_t)BB * CUT * HD;               // [384*512]  frag-ordered W
  u16* VTg = W3F + (size_t)384 * 512;                  // [B*64*T]   V transposed

  wtrans_k<<<768, 256, 0, stream>>>(Wk, Wv, Wq, W3F);
  proj_k<<<512, 256, 0, stream>>>(x, W3F, bk, bv, bq, Kb, Vb, Qb);
  vtrans_k<<<512, 256, 0, stream>>>(Vb, VTg);
  attn_k<<<512, 512, 0, stream>>>(Qb, Kb, VTg, out);
}

// Round 5
// 58.458 us; speedup vs baseline: 2.1820x; 1.6922x over previous
//
#include <hip/hip_runtime.h>

#define BB 4
#define TT 4096
#define CUT 2048
#define CE 1024
#define HD 64
#define QSC 0.045084220027780106f   // 1024^-0.5 * log2(e)

typedef unsigned short u16;
typedef unsigned int u32;
typedef __attribute__((ext_vector_type(8))) short bf16x8;
typedef __attribute__((ext_vector_type(4))) float f32x4;

__device__ __forceinline__ u16 f2b(float f) {
  union { float f; unsigned u; } v; v.f = f;
  unsigned r = v.u + 0x7fffu + ((v.u >> 16) & 1u);   // RNE to bf16
  return (u16)(r >> 16);
}

__device__ __forceinline__ u32 cvtpk(float lo, float hi) {
  u32 r;
  asm("v_cvt_pk_bf16_f32 %0, %1, %2" : "=v"(r) : "v"(lo), "v"(hi));
  return r;
}

// ---- Kernel 1: W3F = W in MFMA B-fragment order (contiguous 1KB wave loads) ----
__global__ void wtrans_k(const float* __restrict__ Wk, const float* __restrict__ Wv,
                         const float* __restrict__ Wq, u16* __restrict__ w3f) {
  int id = blockIdx.x * 256 + threadIdx.x;     // 196608 total
  int j    = id & 7;
  int lane = (id >> 3) & 63;
  int f    = id >> 9;                          // 0..383
  int kstep = f & 31;
  int mnt   = f >> 5;
  int m  = mnt >> 2;
  int nt = mnt & 3;
  int k   = kstep * 32 + (lane >> 4) * 8 + j;
  int col = nt * 16 + (lane & 15);
  const float* W = (m == 0) ? Wk : (m == 1) ? Wv : Wq;
  w3f[id] = f2b(W[k * 64 + col]);
}

// ---- Kernel 2: QKV projection (unchanged from round 4) ----
__launch_bounds__(256, 2)
__global__ void proj_k(const float* __restrict__ x, const u16* __restrict__ w3f,
                       const float* __restrict__ bk, const float* __restrict__ bv,
                       const float* __restrict__ bq,
                       u16* __restrict__ Kb, u16* __restrict__ Vb, u16* __restrict__ Qb) {
  __shared__ f32x4 cl[2][2][12][64];            // 48KB combine buffer
  const int tid  = threadIdx.x;
  const int lane = tid & 63;
  const int kh   = tid >> 6;                    // wave = K-split 0..3
  const int l15  = lane & 15;
  const int g    = lane >> 4;
  const int r0   = blockIdx.x * 32;

  f32x4 acc[2][12];
  #pragma unroll
  for (int h = 0; h < 2; ++h)
    #pragma unroll
    for (int t = 0; t < 12; ++t) acc[h][t] = (f32x4){0.f, 0.f, 0.f, 0.f};

  const float* x0 = x + (size_t)(r0 + l15) * CE;
  const float* x1 = x + (size_t)(r0 + 16 + l15) * CE;

  #pragma unroll
  for (int kc = 0; kc < 8; ++kc) {
    const int ko = kh * 256 + kc * 32 + g * 8;
    bf16x8 a0, a1;
    {
      f32x4 xa = *(const f32x4*)(x0 + ko);
      f32x4 xb = *(const f32x4*)(x0 + ko + 4);
      f32x4 ya = *(const f32x4*)(x1 + ko);
      f32x4 yb = *(const f32x4*)(x1 + ko + 4);
      #pragma unroll
      for (int j = 0; j < 4; ++j) {
        a0[j] = (short)f2b(xa[j]); a0[j + 4] = (short)f2b(xb[j]);
        a1[j] = (short)f2b(ya[j]); a1[j + 4] = (short)f2b(yb[j]);
      }
    }
    const int kstep = kh * 8 + kc;
    #pragma unroll
    for (int mnt = 0; mnt < 12; ++mnt) {
      bf16x8 bfr = *(const bf16x8*)&w3f[(size_t)(mnt * 32 + kstep) * 512 + lane * 8];
      acc[0][mnt] = __builtin_amdgcn_mfma_f32_16x16x32_bf16(a0, bfr, acc[0][mnt], 0, 0, 0);
      acc[1][mnt] = __builtin_amdgcn_mfma_f32_16x16x32_bf16(a1, bfr, acc[1][mnt], 0, 0, 0);
    }
  }

  if (kh >= 2) {
    #pragma unroll
    for (int h = 0; h < 2; ++h)
      #pragma unroll
      for (int t = 0; t < 12; ++t) cl[kh - 2][h][t][lane] = acc[h][t];
  }
  __syncthreads();
  if (kh < 2) {
    #pragma unroll
    for (int h = 0; h < 2; ++h)
      #pragma unroll
      for (int t = 0; t < 12; ++t) acc[h][t] += cl[kh][h][t][lane];
  }
  __syncthreads();
  if (kh == 1) {
    #pragma unroll
    for (int h = 0; h < 2; ++h)
      #pragma unroll
      for (int t = 0; t < 12; ++t) cl[0][h][t][lane] = acc[h][t];
  }
  __syncthreads();
  if (kh == 0) {
    #pragma unroll
    for (int h = 0; h < 2; ++h)
      #pragma unroll
      for (int t = 0; t < 12; ++t) acc[h][t] += cl[0][h][t][lane];

    #pragma unroll
    for (int h = 0; h < 2; ++h) {
      const int orow0 = r0 + h * 16 + g * 4;    // C/D: row=(lane>>4)*4+r, col=l15
      #pragma unroll
      for (int m = 0; m < 3; ++m) {
        const float* bias = (m == 0) ? bk : (m == 1) ? bv : bq;
        #pragma unroll
        for (int nt = 0; nt < 4; ++nt) {
          int col = nt * 16 + l15;
          float bc = bias[col];
          #pragma unroll
          for (int r = 0; r < 4; ++r) {
            int orow = orow0 + r;
            float val = acc[h][m * 4 + nt][r] + bc;
            if (m == 0)      Kb[(size_t)orow * HD + col] = f2b(val);
            else if (m == 1) Vb[(size_t)orow * HD + col] = f2b(val);
            else {
              int t = orow & (TT - 1);
              if (t >= CUT)  // Q pre-scaled by 1024^-0.5 * log2(e) for exp2 softmax
                Qb[((size_t)(orow >> 12) * CUT + (t - CUT)) * HD + col] = f2b(val * QSC);
            }
          }
        }
      }
    }
  }
}

// ---- Kernel 2b: repack K and V into MFMA-fragment order. ----
// KF[((b*64+c)*8 + kt*2+h)*512 + lane*8+j] = K[b][c*64+kt*16+(lane&15)][h*32+(lane>>4)*8+j]
// VF[((b*64+c)*8 + c2*4+dt)*512 + lane*8+j] = V[b][c*64+c2*32+(lane>>4)*8+j][dt*16+(lane&15)]
// Attn's per-chunk loads become single contiguous 1KB global_load_dwordx4 per wave.
__global__ void kvtrans_k(const u16* __restrict__ Kb, const u16* __restrict__ Vb,
                          u16* __restrict__ KF, u16* __restrict__ VF) {
  int id = blockIdx.x * 256 + threadIdx.x;     // 262144 total
  int lane = id & 63;
  int f    = (id >> 6) & 7;
  int c    = (id >> 9) & 63;
  int sel  = id >> 15;                         // 0..3: K batches, 4..7: V batches
  int l15 = lane & 15, g = lane >> 4;
  if (sel < 4) {
    int b = sel;
    int kt = f >> 1, h = f & 1;
    int row = c * 64 + kt * 16 + l15;
    bf16x8 v = *(const bf16x8*)&Kb[((size_t)b * TT + row) * HD + h * 32 + g * 8];
    *(bf16x8*)&KF[(((size_t)b * 64 + c) * 8 + f) * 512 + lane * 8] = v;
  } else {
    int b = sel - 4;
    int c2 = f >> 2, dt = f & 3;
    int row = c * 64 + c2 * 32 + g * 8;
    int d = dt * 16 + l15;
    const u16* src = Vb + ((size_t)b * TT + row) * HD + d;
    bf16x8 v;
    #pragma unroll
    for (int j = 0; j < 8; ++j) v[j] = (short)src[j * HD];
    *(bf16x8*)&VF[(((size_t)b * 64 + c) * 8 + f) * 512 + lane * 8] = v;
  }
}

// ---- Kernel 3: attention. Fixed-max exp2 softmax, 8-way KV-split, frag-order
// K/V (contiguous 1KB loads), all loads issued at chunk top, balanced tile map.
__launch_bounds__(512, 4)
__global__ void attn_k(const u16* __restrict__ Qb, const u16* __restrict__ KF,
                       const u16* __restrict__ VF, float* __restrict__ out) {
  __shared__ u32   PLd[8][16][36];              // per-wave P (bf16 pairs): [q][key/2]
  __shared__ float OO[8][16][66];               // per-wave unnormalized O: [q][d]
  __shared__ float OL[8][16];                   // per-wave l-sum per q
  const int tid  = threadIdx.x;
  const int lane = tid & 63;
  const int wv   = tid >> 6;
  const int l15  = lane & 15;
  const int g    = lane >> 4;
  // balanced map: XCD (= id mod 8, empirically) gets one batch, uniform tile sweep
  const int id   = blockIdx.x;                  // 0..511
  const int b    = id & 3;
  const int i0   = (id >> 2) * 16;

  const int qabs = CUT + i0 + l15;              // abs pos of this lane's q column (S^T)
  const int qmin = CUT + i0;

  const u16* qrow = Qb + ((size_t)b * CUT + i0 + l15) * HD;
  bf16x8 qf0 = *(const bf16x8*)&qrow[g * 8];
  bf16x8 qf1 = *(const bf16x8*)&qrow[32 + g * 8];

  f32x4 o[4];
  #pragma unroll
  for (int dt = 0; dt < 4; ++dt) o[dt] = (f32x4){0.f, 0.f, 0.f, 0.f};
  float lsum = 0.f;

  const int kv_end = CUT + i0 + 16;
  const int nch = (kv_end + 63) >> 6;           // 33..64 chunks
  const u16* KFb = KF + (size_t)b * 64 * 8 * 512;
  const u16* VFb = VF + (size_t)b * 64 * 8 * 512;

  for (int c = wv; c < nch; c += 8) {
    const int kv0 = c << 6;

    // ---- issue ALL loads up front: 8 K-frags then 8 V-frags (1KB each) ----
    const u16* kp = KFb + (size_t)c * 4096 + lane * 8;
    bf16x8 ka[4][2];
    #pragma unroll
    for (int kt = 0; kt < 4; ++kt) {
      ka[kt][0] = *(const bf16x8*)(kp + (kt * 2 + 0) * 512);
      ka[kt][1] = *(const bf16x8*)(kp + (kt * 2 + 1) * 512);
    }
    const u16* vp = VFb + (size_t)c * 4096 + lane * 8;
    bf16x8 va[2][4];
    #pragma unroll
    for (int c2 = 0; c2 < 2; ++c2)
      #pragma unroll
      for (int dt = 0; dt < 4; ++dt)
        va[c2][dt] = *(const bf16x8*)(vp + (c2 * 4 + dt) * 512);

    // ---- QK^T ----
    f32x4 st[4];
    __builtin_amdgcn_s_setprio(1);
    #pragma unroll
    for (int kt = 0; kt < 4; ++kt) {
      f32x4 s = (f32x4){0.f, 0.f, 0.f, 0.f};
      s = __builtin_amdgcn_mfma_f32_16x16x32_bf16(ka[kt][0], qf0, s, 0, 0, 0);
      s = __builtin_amdgcn_mfma_f32_16x16x32_bf16(ka[kt][1], qf1, s, 0, 0, 0);
      st[kt] = s;
    }
    __builtin_amdgcn_s_setprio(0);

    // ---- p = 2^s (scale*log2e folded into Q; fixed max) ----
    if (kv0 + 63 <= qmin) {                     // wave-uniform: fully unmasked chunk
      #pragma unroll
      for (int kt = 0; kt < 4; ++kt)
        #pragma unroll
        for (int r = 0; r < 4; ++r) {
          float p = exp2f(st[kt][r]);
          st[kt][r] = p;
          lsum += p;
        }
    } else {
      #pragma unroll
      for (int kt = 0; kt < 4; ++kt)
        #pragma unroll
        for (int r = 0; r < 4; ++r) {
          int key = kv0 + kt * 16 + g * 4 + r;
          float p = exp2f(st[kt][r]);
          p = (key <= qabs) ? p : 0.f;
          st[kt][r] = p;
          lsum += p;
        }
    }

    #pragma unroll
    for (int kt = 0; kt < 4; ++kt) {            // pack P->bf16, wave-private LDS
      u32 d0 = cvtpk(st[kt][0], st[kt][1]);
      u32 d1 = cvtpk(st[kt][2], st[kt][3]);
      u32* p = &PLd[wv][l15][kt * 8 + g * 2];
      p[0] = d0; p[1] = d1;
    }

    // ---- O += P @ V (va long in flight -> complete) ----
    __builtin_amdgcn_s_setprio(1);
    #pragma unroll
    for (int c2 = 0; c2 < 2; ++c2) {
      bf16x8 pa = *(const bf16x8*)&PLd[wv][l15][c2 * 16 + g * 4];
      #pragma unroll
      for (int dt = 0; dt < 4; ++dt)
        o[dt] = __builtin_amdgcn_mfma_f32_16x16x32_bf16(pa, va[c2][dt], o[dt], 0, 0, 0);
    }
    __builtin_amdgcn_s_setprio(0);
  }

  // ---- l reduce over g-groups ----
  lsum += __shfl_xor(lsum, 16);
  lsum += __shfl_xor(lsum, 32);
  if (lane < 16) OL[wv][l15] = lsum;
  #pragma unroll
  for (int dt = 0; dt < 4; ++dt)
    #pragma unroll
    for (int r = 0; r < 4; ++r)
      OO[wv][g * 4 + r][dt * 16 + l15] = o[dt][r];
  __syncthreads();

  // ---- combine across the 8 KV-split waves: pure sums, then normalize ----
  #pragma unroll
  for (int e = tid; e < 1024; e += 512) {
    int q = e >> 6, d = e & 63;
    float L = 0.f, O = 0.f;
    #pragma unroll
    for (int w = 0; w < 8; ++w) { L += OL[w][q]; O += OO[w][q][d]; }
    out[((size_t)b * CUT + i0 + q) * HD + d] = O / L;
  }
}

extern "C" void kernel_launch(void* const* d_in, const int* in_sizes, int n_in,
                              void* d_out, int out_size, void* d_ws, size_t ws_size,
                              hipStream_t stream) {
  const float* x  = (const float*)d_in[0];
  const float* Wq = (const float*)d_in[1];
  const float* bq = (const float*)d_in[2];
  const float* Wk = (const float*)d_in[3];
  const float* bk = (const float*)d_in[4];
  const float* Wv = (const float*)d_in[5];
  const float* bv = (const float*)d_in[6];
  float* out = (float*)d_out;

  u16* Kb  = (u16*)d_ws;                               // [B*T*64]   bf16, row-major
  u16* Vb  = Kb + (size_t)BB * TT * HD;                // [B*T*64]
  u16* Qb  = Vb + (size_t)BB * TT * HD;                // [B*CUT*64] (pre-scaled)
  u16* W3F = Qb + (size_t)BB * CUT * HD;               // [384*512]  frag-ordered W
  u16* KF  = W3F + (size_t)384 * 512;                  // [B*64*8*512] frag-ordered K
  u16* VF  = KF + (size_t)BB * 64 * 8 * 512;           // [B*64*8*512] frag-ordered V

  wtrans_k<<<768, 256, 0, stream>>>(Wk, Wv, Wq, W3F);
  proj_k<<<512, 256, 0, stream>>>(x, W3F, bk, bv, bq, Kb, Vb, Qb);
  kvtrans_k<<<1024, 256, 0, stream>>>(Kb, Vb, KF, VF);
  attn_k<<<512, 512, 0, stream>>>(Qb, KF, VF, out);
}

// Round 6
// 53.409 us; speedup vs baseline: 2.3882x; 1.0945x over previous
//
#include <hip/hip_runtime.h>

#define BB 4
#define TT 4096
#define CUT 2048
#define CE 1024
#define HD 64
#define QSC 0.045084220027780106f   // 1024^-0.5 * log2(e)

typedef unsigned short u16;
typedef unsigned int u32;
typedef __attribute__((ext_vector_type(8))) short bf16x8;
typedef __attribute__((ext_vector_type(4))) float f32x4;

__device__ __forceinline__ u16 f2b(float f) {
  union { float f; unsigned u; } v; v.f = f;
  unsigned r = v.u + 0x7fffu + ((v.u >> 16) & 1u);   // RNE to bf16
  return (u16)(r >> 16);
}

__device__ __forceinline__ u32 cvtpk(float lo, float hi) {
  u32 r;
  asm("v_cvt_pk_bf16_f32 %0, %1, %2" : "=v"(r) : "v"(lo), "v"(hi));
  return r;
}

// ---- Kernel 1: W3F = W in MFMA B-fragment order (contiguous 1KB wave loads) ----
__global__ void wtrans_k(const float* __restrict__ Wk, const float* __restrict__ Wv,
                         const float* __restrict__ Wq, u16* __restrict__ w3f) {
  int id = blockIdx.x * 256 + threadIdx.x;     // 196608 total
  int j    = id & 7;
  int lane = (id >> 3) & 63;
  int f    = id >> 9;                          // 0..383
  int kstep = f & 31;
  int mnt   = f >> 5;
  int m  = mnt >> 2;
  int nt = mnt & 3;
  int k   = kstep * 32 + (lane >> 4) * 8 + j;
  int col = nt * 16 + (lane & 15);
  const float* W = (m == 0) ? Wk : (m == 1) ? Wv : Wq;
  w3f[id] = f2b(W[k * 64 + col]);
}

// ---- Kernel 2: QKV projection with x double-buffer; epilogue writes K/V
// directly in MFMA-fragment order (kvtrans fused) plus row-major pre-scaled Q.
__launch_bounds__(256, 2)
__global__ void proj_k(const float* __restrict__ x, const u16* __restrict__ w3f,
                       const float* __restrict__ bk, const float* __restrict__ bv,
                       const float* __restrict__ bq,
                       u16* __restrict__ KF, u16* __restrict__ VF, u16* __restrict__ Qb) {
  __shared__ f32x4 cl[2][2][12][64];            // 48KB combine buffer
  const int tid  = threadIdx.x;
  const int lane = tid & 63;
  const int kh   = tid >> 6;                    // wave = K-split 0..3
  const int l15  = lane & 15;
  const int g    = lane >> 4;
  const int r0   = blockIdx.x * 32;

  f32x4 acc[2][12];
  #pragma unroll
  for (int h = 0; h < 2; ++h)
    #pragma unroll
    for (int t = 0; t < 12; ++t) acc[h][t] = (f32x4){0.f, 0.f, 0.f, 0.f};

  const float* x0 = x + (size_t)(r0 + l15) * CE;
  const float* x1 = x + (size_t)(r0 + 16 + l15) * CE;

  f32x4 xs[2][4];                               // x ping-pong (idx is unroll-constant)
  {
    const int ko = kh * 256 + g * 8;
    xs[0][0] = *(const f32x4*)(x0 + ko);
    xs[0][1] = *(const f32x4*)(x0 + ko + 4);
    xs[0][2] = *(const f32x4*)(x1 + ko);
    xs[0][3] = *(const f32x4*)(x1 + ko + 4);
  }

  #pragma unroll
  for (int kc = 0; kc < 8; ++kc) {
    const int cur = kc & 1, nxt = cur ^ 1;
    if (kc < 7) {                               // prefetch next kc's x (HBM) early
      const int ko = kh * 256 + (kc + 1) * 32 + g * 8;
      xs[nxt][0] = *(const f32x4*)(x0 + ko);
      xs[nxt][1] = *(const f32x4*)(x0 + ko + 4);
      xs[nxt][2] = *(const f32x4*)(x1 + ko);
      xs[nxt][3] = *(const f32x4*)(x1 + ko + 4);
    }
    bf16x8 a0, a1;
    #pragma unroll
    for (int j = 0; j < 4; ++j) {
      a0[j] = (short)f2b(xs[cur][0][j]); a0[j + 4] = (short)f2b(xs[cur][1][j]);
      a1[j] = (short)f2b(xs[cur][2][j]); a1[j + 4] = (short)f2b(xs[cur][3][j]);
    }
    const int kstep = kh * 8 + kc;
    #pragma unroll
    for (int mnt = 0; mnt < 12; ++mnt) {
      bf16x8 bfr = *(const bf16x8*)&w3f[(size_t)(mnt * 32 + kstep) * 512 + lane * 8];
      acc[0][mnt] = __builtin_amdgcn_mfma_f32_16x16x32_bf16(a0, bfr, acc[0][mnt], 0, 0, 0);
      acc[1][mnt] = __builtin_amdgcn_mfma_f32_16x16x32_bf16(a1, bfr, acc[1][mnt], 0, 0, 0);
    }
  }

  // ---- K-split tree combine in LDS: (0+=2, 1+=3), then (0+=1) ----
  if (kh >= 2) {
    #pragma unroll
    for (int h = 0; h < 2; ++h)
      #pragma unroll
      for (int t = 0; t < 12; ++t) cl[kh - 2][h][t][lane] = acc[h][t];
  }
  __syncthreads();
  if (kh < 2) {
    #pragma unroll
    for (int h = 0; h < 2; ++h)
      #pragma unroll
      for (int t = 0; t < 12; ++t) acc[h][t] += cl[kh][h][t][lane];
  }
  __syncthreads();
  if (kh == 1) {
    #pragma unroll
    for (int h = 0; h < 2; ++h)
      #pragma unroll
      for (int t = 0; t < 12; ++t) cl[0][h][t][lane] = acc[h][t];
  }
  __syncthreads();
  if (kh == 0) {
    #pragma unroll
    for (int h = 0; h < 2; ++h)
      #pragma unroll
      for (int t = 0; t < 12; ++t) acc[h][t] += cl[0][h][t][lane];
    // share K (t=0..3) and V (t=4..7) parts for waves 1,2
    #pragma unroll
    for (int h = 0; h < 2; ++h)
      #pragma unroll
      for (int t = 0; t < 8; ++t) cl[1][h][t][lane] = acc[h][t];
  }
  __syncthreads();

  const int b    = r0 >> 12;
  const int cch  = (r0 >> 6) & 63;
  const int half = (r0 >> 5) & 1;

  if (kh == 0) {
    // ---- Q: row-major, pre-scaled (from registers; C/D row=(lane>>4)*4+r) ----
    const int t0 = r0 & (TT - 1);
    if (t0 >= CUT) {
      const int trow = t0 - CUT;
      #pragma unroll
      for (int h = 0; h < 2; ++h)
        #pragma unroll
        for (int nt = 0; nt < 4; ++nt) {
          int col = nt * 16 + l15;
          float bc = bq[col];
          #pragma unroll
          for (int r = 0; r < 4; ++r) {
            int qrow = trow + h * 16 + g * 4 + r;
            Qb[((size_t)b * CUT + qrow) * HD + col] = f2b((acc[h][8 + nt][r] + bc) * QSC);
          }
        }
    }
  } else if (kh == 1) {
    // ---- K-frags: KF[(b*64+c)*8 + kt*2+hk][lane'*8+j'] ----
    u16* KFc = KF + ((size_t)(b * 64 + cch) * 8) * 512;
    #pragma unroll
    for (int h = 0; h < 2; ++h) {
      const int kt2 = (half * 2 + h) * 2;
      #pragma unroll
      for (int nt = 0; nt < 4; ++nt) {
        int col = nt * 16 + l15;
        float bc = bk[col];
        f32x4 v = cl[1][h][nt][lane];
        const int off = (kt2 + (nt >> 1)) * 512 + 128 * ((nt & 1) * 2 + (l15 >> 3)) + (l15 & 7);
        #pragma unroll
        for (int r = 0; r < 4; ++r)
          KFc[off + (g * 4 + r) * 8] = f2b(v[r] + bc);
      }
    }
  } else if (kh == 2) {
    // ---- V-frags: VF[(b*64+c)*8 + c2*4+dt][( (d&15) + 16*(tt>>3) )*8 + (tt&7)] ----
    u16* VFc = VF + ((size_t)(b * 64 + cch) * 8) * 512;
    #pragma unroll
    for (int h = 0; h < 2; ++h) {
      #pragma unroll
      for (int nt = 0; nt < 4; ++nt) {
        int col = nt * 16 + l15;
        float bc = bv[col];
        f32x4 v = cl[1][h][4 + nt][lane];
        #pragma unroll
        for (int r = 0; r < 4; ++r) {
          int tt = h * 16 + g * 4 + r;
          VFc[(half * 4 + nt) * 512 + (l15 + 16 * (tt >> 3)) * 8 + (tt & 7)] = f2b(v[r] + bc);
        }
      }
    }
  }
}

// ---- Kernel 3: attention (UNCHANGED from round 5 for clean attribution) ----
__launch_bounds__(512, 4)
__global__ void attn_k(const u16* __restrict__ Qb, const u16* __restrict__ KF,
                       const u16* __restrict__ VF, float* __restrict__ out) {
  __shared__ u32   PLd[8][16][36];              // per-wave P (bf16 pairs): [q][key/2]
  __shared__ float OO[8][16][66];               // per-wave unnormalized O: [q][d]
  __shared__ float OL[8][16];                   // per-wave l-sum per q
  const int tid  = threadIdx.x;
  const int lane = tid & 63;
  const int wv   = tid >> 6;
  const int l15  = lane & 15;
  const int g    = lane >> 4;
  const int id   = blockIdx.x;                  // 0..511
  const int b    = id & 3;
  const int i0   = (id >> 2) * 16;

  const int qabs = CUT + i0 + l15;              // abs pos of this lane's q column (S^T)
  const int qmin = CUT + i0;

  const u16* qrow = Qb + ((size_t)b * CUT + i0 + l15) * HD;
  bf16x8 qf0 = *(const bf16x8*)&qrow[g * 8];
  bf16x8 qf1 = *(const bf16x8*)&qrow[32 + g * 8];

  f32x4 o[4];
  #pragma unroll
  for (int dt = 0; dt < 4; ++dt) o[dt] = (f32x4){0.f, 0.f, 0.f, 0.f};
  float lsum = 0.f;

  const int kv_end = CUT + i0 + 16;
  const int nch = (kv_end + 63) >> 6;           // 33..64 chunks
  const u16* KFb = KF + (size_t)b * 64 * 8 * 512;
  const u16* VFb = VF + (size_t)b * 64 * 8 * 512;

  for (int c = wv; c < nch; c += 8) {
    const int kv0 = c << 6;

    const u16* kp = KFb + (size_t)c * 4096 + lane * 8;
    bf16x8 ka[4][2];
    #pragma unroll
    for (int kt = 0; kt < 4; ++kt) {
      ka[kt][0] = *(const bf16x8*)(kp + (kt * 2 + 0) * 512);
      ka[kt][1] = *(const bf16x8*)(kp + (kt * 2 + 1) * 512);
    }
    const u16* vp = VFb + (size_t)c * 4096 + lane * 8;
    bf16x8 va[2][4];
    #pragma unroll
    for (int c2 = 0; c2 < 2; ++c2)
      #pragma unroll
      for (int dt = 0; dt < 4; ++dt)
        va[c2][dt] = *(const bf16x8*)(vp + (c2 * 4 + dt) * 512);

    f32x4 st[4];
    __builtin_amdgcn_s_setprio(1);
    #pragma unroll
    for (int kt = 0; kt < 4; ++kt) {
      f32x4 s = (f32x4){0.f, 0.f, 0.f, 0.f};
      s = __builtin_amdgcn_mfma_f32_16x16x32_bf16(ka[kt][0], qf0, s, 0, 0, 0);
      s = __builtin_amdgcn_mfma_f32_16x16x32_bf16(ka[kt][1], qf1, s, 0, 0, 0);
      st[kt] = s;
    }
    __builtin_amdgcn_s_setprio(0);

    if (kv0 + 63 <= qmin) {                     // wave-uniform: fully unmasked chunk
      #pragma unroll
      for (int kt = 0; kt < 4; ++kt)
        #pragma unroll
        for (int r = 0; r < 4; ++r) {
          float p = exp2f(st[kt][r]);
          st[kt][r] = p;
          lsum += p;
        }
    } else {
      #pragma unroll
      for (int kt = 0; kt < 4; ++kt)
        #pragma unroll
        for (int r = 0; r < 4; ++r) {
          int key = kv0 + kt * 16 + g * 4 + r;
          float p = exp2f(st[kt][r]);
          p = (key <= qabs) ? p : 0.f;
          st[kt][r] = p;
          lsum += p;
        }
    }

    #pragma unroll
    for (int kt = 0; kt < 4; ++kt) {            // pack P->bf16, wave-private LDS
      u32 d0 = cvtpk(st[kt][0], st[kt][1]);
      u32 d1 = cvtpk(st[kt][2], st[kt][3]);
      u32* p = &PLd[wv][l15][kt * 8 + g * 2];
      p[0] = d0; p[1] = d1;
    }

    __builtin_amdgcn_s_setprio(1);
    #pragma unroll
    for (int c2 = 0; c2 < 2; ++c2) {
      bf16x8 pa = *(const bf16x8*)&PLd[wv][l15][c2 * 16 + g * 4];
      #pragma unroll
      for (int dt = 0; dt < 4; ++dt)
        o[dt] = __builtin_amdgcn_mfma_f32_16x16x32_bf16(pa, va[c2][dt], o[dt], 0, 0, 0);
    }
    __builtin_amdgcn_s_setprio(0);
  }

  lsum += __shfl_xor(lsum, 16);
  lsum += __shfl_xor(lsum, 32);
  if (lane < 16) OL[wv][l15] = lsum;
  #pragma unroll
  for (int dt = 0; dt < 4; ++dt)
    #pragma unroll
    for (int r = 0; r < 4; ++r)
      OO[wv][g * 4 + r][dt * 16 + l15] = o[dt][r];
  __syncthreads();

  #pragma unroll
  for (int e = tid; e < 1024; e += 512) {
    int q = e >> 6, d = e & 63;
    float L = 0.f, O = 0.f;
    #pragma unroll
    for (int w = 0; w < 8; ++w) { L += OL[w][q]; O += OO[w][q][d]; }
    out[((size_t)b * CUT + i0 + q) * HD + d] = O / L;
  }
}

extern "C" void kernel_launch(void* const* d_in, const int* in_sizes, int n_in,
                              void* d_out, int out_size, void* d_ws, size_t ws_size,
                              hipStream_t stream) {
  const float* x  = (const float*)d_in[0];
  const float* Wq = (const float*)d_in[1];
  const float* bq = (const float*)d_in[2];
  const float* Wk = (const float*)d_in[3];
  const float* bk = (const float*)d_in[4];
  const float* Wv = (const float*)d_in[5];
  const float* bv = (const float*)d_in[6];
  float* out = (float*)d_out;

  u16* Qb  = (u16*)d_ws;                               // [B*CUT*64] (pre-scaled)
  u16* W3F = Qb + (size_t)BB * CUT * HD;               // [384*512]  frag-ordered W
  u16* KF  = W3F + (size_t)384 * 512;                  // [B*64*8*512] frag-ordered K
  u16* VF  = KF + (size_t)BB * 64 * 8 * 512;           // [B*64*8*512] frag-ordered V

  wtrans_k<<<768, 256, 0, stream>>>(Wk, Wv, Wq, W3F);
  proj_k<<<512, 256, 0, stream>>>(x, W3F, bk, bv, bq, KF, VF, Qb);
  attn_k<<<512, 512, 0, stream>>>(Qb, KF, VF, out);
}

// Round 7
// 52.313 us; speedup vs baseline: 2.4383x; 1.0210x over previous
//
#include <hip/hip_runtime.h>

#define BB 4
#define TT 4096
#define CUT 2048
#define CE 1024
#define HD 64
#define QSC 0.045084220027780106f   // 1024^-0.5 * log2(e)

typedef unsigned short u16;
typedef unsigned int u32;
typedef __attribute__((ext_vector_type(8))) short bf16x8;
typedef __attribute__((ext_vector_type(4))) float f32x4;

__device__ __forceinline__ u16 f2b(float f) {
  union { float f; unsigned u; } v; v.f = f;
  unsigned r = v.u + 0x7fffu + ((v.u >> 16) & 1u);   // RNE to bf16
  return (u16)(r >> 16);
}

__device__ __forceinline__ u32 cvtpk(float lo, float hi) {
  u32 r;
  asm("v_cvt_pk_bf16_f32 %0, %1, %2" : "=v"(r) : "v"(lo), "v"(hi));
  return r;
}

// ---- Kernel 1: W3F = W in MFMA B-fragment order (contiguous 1KB wave loads) ----
__global__ void wtrans_k(const float* __restrict__ Wk, const float* __restrict__ Wv,
                         const float* __restrict__ Wq, u16* __restrict__ w3f) {
  int id = blockIdx.x * 256 + threadIdx.x;     // 196608 total
  int j    = id & 7;
  int lane = (id >> 3) & 63;
  int f    = id >> 9;                          // 0..383
  int kstep = f & 31;
  int mnt   = f >> 5;
  int m  = mnt >> 2;
  int nt = mnt & 3;
  int k   = kstep * 32 + (lane >> 4) * 8 + j;
  int col = nt * 16 + (lane & 15);
  const float* W = (m == 0) ? Wk : (m == 1) ? Wv : Wq;
  w3f[id] = f2b(W[k * 64 + col]);
}

// ---- Kernel 2: QKV projection. W-frag loads batched into a 12-wide register
// cluster (issue all, then consume) so only ONE L2 latency is exposed per kc;
// x-prefetch issued AFTER the cluster so it rides across the whole iteration.
// Epilogue writes K/V directly in MFMA-fragment order + row-major pre-scaled Q.
__launch_bounds__(256, 2)
__global__ void proj_k(const float* __restrict__ x, const u16* __restrict__ w3f,
                       const float* __restrict__ bk, const float* __restrict__ bv,
                       const float* __restrict__ bq,
                       u16* __restrict__ KF, u16* __restrict__ VF, u16* __restrict__ Qb) {
  __shared__ f32x4 cl[2][2][12][64];            // 48KB combine buffer
  const int tid  = threadIdx.x;
  const int lane = tid & 63;
  const int kh   = tid >> 6;                    // wave = K-split 0..3
  const int l15  = lane & 15;
  const int g    = lane >> 4;
  const int r0   = blockIdx.x * 32;

  f32x4 acc[2][12];
  #pragma unroll
  for (int h = 0; h < 2; ++h)
    #pragma unroll
    for (int t = 0; t < 12; ++t) acc[h][t] = (f32x4){0.f, 0.f, 0.f, 0.f};

  const float* x0 = x + (size_t)(r0 + l15) * CE;
  const float* x1 = x + (size_t)(r0 + 16 + l15) * CE;

  f32x4 xs[2][4];                               // x ping-pong (idx is unroll-constant)
  {
    const int ko = kh * 256 + g * 8;
    xs[0][0] = *(const f32x4*)(x0 + ko);
    xs[0][1] = *(const f32x4*)(x0 + ko + 4);
    xs[0][2] = *(const f32x4*)(x1 + ko);
    xs[0][3] = *(const f32x4*)(x1 + ko + 4);
  }

  #pragma unroll
  for (int kc = 0; kc < 8; ++kc) {
    const int cur = kc & 1, nxt = cur ^ 1;
    const int kstep = kh * 8 + kc;

    bf16x8 wfr[12];                             // 12 W-frag loads issued as a cluster
    #pragma unroll
    for (int mnt = 0; mnt < 12; ++mnt)
      wfr[mnt] = *(const bf16x8*)&w3f[(size_t)(mnt * 32 + kstep) * 512 + lane * 8];

    if (kc < 7) {                               // x-prefetch AFTER the w3f cluster
      const int ko = kh * 256 + (kc + 1) * 32 + g * 8;
      xs[nxt][0] = *(const f32x4*)(x0 + ko);
      xs[nxt][1] = *(const f32x4*)(x0 + ko + 4);
      xs[nxt][2] = *(const f32x4*)(x1 + ko);
      xs[nxt][3] = *(const f32x4*)(x1 + ko + 4);
    }

    bf16x8 a0, a1;
    #pragma unroll
    for (int j = 0; j < 4; ++j) {
      a0[j] = (short)f2b(xs[cur][0][j]); a0[j + 4] = (short)f2b(xs[cur][1][j]);
      a1[j] = (short)f2b(xs[cur][2][j]); a1[j + 4] = (short)f2b(xs[cur][3][j]);
    }

    #pragma unroll
    for (int mnt = 0; mnt < 12; ++mnt) {
      acc[0][mnt] = __builtin_amdgcn_mfma_f32_16x16x32_bf16(a0, wfr[mnt], acc[0][mnt], 0, 0, 0);
      acc[1][mnt] = __builtin_amdgcn_mfma_f32_16x16x32_bf16(a1, wfr[mnt], acc[1][mnt], 0, 0, 0);
    }
  }

  // ---- K-split tree combine in LDS: (0+=2, 1+=3), then (0+=1) ----
  if (kh >= 2) {
    #pragma unroll
    for (int h = 0; h < 2; ++h)
      #pragma unroll
      for (int t = 0; t < 12; ++t) cl[kh - 2][h][t][lane] = acc[h][t];
  }
  __syncthreads();
  if (kh < 2) {
    #pragma unroll
    for (int h = 0; h < 2; ++h)
      #pragma unroll
      for (int t = 0; t < 12; ++t) acc[h][t] += cl[kh][h][t][lane];
  }
  __syncthreads();
  if (kh == 1) {
    #pragma unroll
    for (int h = 0; h < 2; ++h)
      #pragma unroll
      for (int t = 0; t < 12; ++t) cl[0][h][t][lane] = acc[h][t];
  }
  __syncthreads();
  if (kh == 0) {
    #pragma unroll
    for (int h = 0; h < 2; ++h)
      #pragma unroll
      for (int t = 0; t < 12; ++t) acc[h][t] += cl[0][h][t][lane];
    // share K (t=0..3) and V (t=4..7) parts for waves 1,2
    #pragma unroll
    for (int h = 0; h < 2; ++h)
      #pragma unroll
      for (int t = 0; t < 8; ++t) cl[1][h][t][lane] = acc[h][t];
  }
  __syncthreads();

  const int b    = r0 >> 12;
  const int cch  = (r0 >> 6) & 63;
  const int half = (r0 >> 5) & 1;

  if (kh == 0) {
    // ---- Q: row-major, pre-scaled (from registers; C/D row=(lane>>4)*4+r) ----
    const int t0 = r0 & (TT - 1);
    if (t0 >= CUT) {
      const int trow = t0 - CUT;
      #pragma unroll
      for (int h = 0; h < 2; ++h)
        #pragma unroll
        for (int nt = 0; nt < 4; ++nt) {
          int col = nt * 16 + l15;
          float bc = bq[col];
          #pragma unroll
          for (int r = 0; r < 4; ++r) {
            int qrow = trow + h * 16 + g * 4 + r;
            Qb[((size_t)b * CUT + qrow) * HD + col] = f2b((acc[h][8 + nt][r] + bc) * QSC);
          }
        }
    }
  } else if (kh == 1) {
    // ---- K-frags: KF[(b*64+c)*8 + kt*2+hk][lane'*8+j'] ----
    u16* KFc = KF + ((size_t)(b * 64 + cch) * 8) * 512;
    #pragma unroll
    for (int h = 0; h < 2; ++h) {
      const int kt2 = (half * 2 + h) * 2;
      #pragma unroll
      for (int nt = 0; nt < 4; ++nt) {
        int col = nt * 16 + l15;
        float bc = bk[col];
        f32x4 v = cl[1][h][nt][lane];
        const int off = (kt2 + (nt >> 1)) * 512 + 128 * ((nt & 1) * 2 + (l15 >> 3)) + (l15 & 7);
        #pragma unroll
        for (int r = 0; r < 4; ++r)
          KFc[off + (g * 4 + r) * 8] = f2b(v[r] + bc);
      }
    }
  } else if (kh == 2) {
    // ---- V-frags: VF[(b*64+c)*8 + c2*4+dt][( (d&15) + 16*(tt>>3) )*8 + (tt&7)] ----
    u16* VFc = VF + ((size_t)(b * 64 + cch) * 8) * 512;
    #pragma unroll
    for (int h = 0; h < 2; ++h) {
      #pragma unroll
      for (int nt = 0; nt < 4; ++nt) {
        int col = nt * 16 + l15;
        float bc = bv[col];
        f32x4 v = cl[1][h][4 + nt][lane];
        #pragma unroll
        for (int r = 0; r < 4; ++r) {
          int tt = h * 16 + g * 4 + r;
          VFc[(half * 4 + nt) * 512 + (l15 + 16 * (tt >> 3)) * 8 + (tt & 7)] = f2b(v[r] + bc);
        }
      }
    }
  }
}

// ---- Kernel 3: attention (UNCHANGED for clean attribution) ----
__launch_bounds__(512, 4)
__global__ void attn_k(const u16* __restrict__ Qb, const u16* __restrict__ KF,
                       const u16* __restrict__ VF, float* __restrict__ out) {
  __shared__ u32   PLd[8][16][36];              // per-wave P (bf16 pairs): [q][key/2]
  __shared__ float OO[8][16][66];               // per-wave unnormalized O: [q][d]
  __shared__ float OL[8][16];                   // per-wave l-sum per q
  const int tid  = threadIdx.x;
  const int lane = tid & 63;
  const int wv   = tid >> 6;
  const int l15  = lane & 15;
  const int g    = lane >> 4;
  const int id   = blockIdx.x;                  // 0..511
  const int b    = id & 3;
  const int i0   = (id >> 2) * 16;

  const int qabs = CUT + i0 + l15;              // abs pos of this lane's q column (S^T)
  const int qmin = CUT + i0;

  const u16* qrow = Qb + ((size_t)b * CUT + i0 + l15) * HD;
  bf16x8 qf0 = *(const bf16x8*)&qrow[g * 8];
  bf16x8 qf1 = *(const bf16x8*)&qrow[32 + g * 8];

  f32x4 o[4];
  #pragma unroll
  for (int dt = 0; dt < 4; ++dt) o[dt] = (f32x4){0.f, 0.f, 0.f, 0.f};
  float lsum = 0.f;

  const int kv_end = CUT + i0 + 16;
  const int nch = (kv_end + 63) >> 6;           // 33..64 chunks
  const u16* KFb = KF + (size_t)b * 64 * 8 * 512;
  const u16* VFb = VF + (size_t)b * 64 * 8 * 512;

  for (int c = wv; c < nch; c += 8) {
    const int kv0 = c << 6;

    const u16* kp = KFb + (size_t)c * 4096 + lane * 8;
    bf16x8 ka[4][2];
    #pragma unroll
    for (int kt = 0; kt < 4; ++kt) {
      ka[kt][0] = *(const bf16x8*)(kp + (kt * 2 + 0) * 512);
      ka[kt][1] = *(const bf16x8*)(kp + (kt * 2 + 1) * 512);
    }
    const u16* vp = VFb + (size_t)c * 4096 + lane * 8;
    bf16x8 va[2][4];
    #pragma unroll
    for (int c2 = 0; c2 < 2; ++c2)
      #pragma unroll
      for (int dt = 0; dt < 4; ++dt)
        va[c2][dt] = *(const bf16x8*)(vp + (c2 * 4 + dt) * 512);

    f32x4 st[4];
    __builtin_amdgcn_s_setprio(1);
    #pragma unroll
    for (int kt = 0; kt < 4; ++kt) {
      f32x4 s = (f32x4){0.f, 0.f, 0.f, 0.f};
      s = __builtin_amdgcn_mfma_f32_16x16x32_bf16(ka[kt][0], qf0, s, 0, 0, 0);
      s = __builtin_amdgcn_mfma_f32_16x16x32_bf16(ka[kt][1], qf1, s, 0, 0, 0);
      st[kt] = s;
    }
    __builtin_amdgcn_s_setprio(0);

    if (kv0 + 63 <= qmin) {                     // wave-uniform: fully unmasked chunk
      #pragma unroll
      for (int kt = 0; kt < 4; ++kt)
        #pragma unroll
        for (int r = 0; r < 4; ++r) {
          float p = exp2f(st[kt][r]);
          st[kt][r] = p;
          lsum += p;
        }
    } else {
      #pragma unroll
      for (int kt = 0; kt < 4; ++kt)
        #pragma unroll
        for (int r = 0; r < 4; ++r) {
          int key = kv0 + kt * 16 + g * 4 + r;
          float p = exp2f(st[kt][r]);
          p = (key <= qabs) ? p : 0.f;
          st[kt][r] = p;
          lsum += p;
        }
    }

    #pragma unroll
    for (int kt = 0; kt < 4; ++kt) {            // pack P->bf16, wave-private LDS
      u32 d0 = cvtpk(st[kt][0], st[kt][1]);
      u32 d1 = cvtpk(st[kt][2], st[kt][3]);
      u32* p = &PLd[wv][l15][kt * 8 + g * 2];
      p[0] = d0; p[1] = d1;
    }

    __builtin_amdgcn_s_setprio(1);
    #pragma unroll
    for (int c2 = 0; c2 < 2; ++c2) {
      bf16x8 pa = *(const bf16x8*)&PLd[wv][l15][c2 * 16 + g * 4];
      #pragma unroll
      for (int dt = 0; dt < 4; ++dt)
        o[dt] = __builtin_amdgcn_mfma_f32_16x16x32_bf16(pa, va[c2][dt], o[dt], 0, 0, 0);
    }
    __builtin_amdgcn_s_setprio(0);
  }

  lsum += __shfl_xor(lsum, 16);
  lsum += __shfl_xor(lsum, 32);
  if (lane < 16) OL[wv][l15] = lsum;
  #pragma unroll
  for (int dt = 0; dt < 4; ++dt)
    #pragma unroll
    for (int r = 0; r < 4; ++r)
      OO[wv][g * 4 + r][dt * 16 + l15] = o[dt][r];
  __syncthreads();

  #pragma unroll
  for (int e = tid; e < 1024; e += 512) {
    int q = e >> 6, d = e & 63;
    float L = 0.f, O = 0.f;
    #pragma unroll
    for (int w = 0; w < 8; ++w) { L += OL[w][q]; O += OO[w][q][d]; }
    out[((size_t)b * CUT + i0 + q) * HD + d] = O / L;
  }
}

extern "C" void kernel_launch(void* const* d_in, const int* in_sizes, int n_in,
                              void* d_out, int out_size, void* d_ws, size_t ws_size,
                              hipStream_t stream) {
  const float* x  = (const float*)d_in[0];
  const float* Wq = (const float*)d_in[1];
  const float* bq = (const float*)d_in[2];
  const float* Wk = (const float*)d_in[3];
  const float* bk = (const float*)d_in[4];
  const float* Wv = (const float*)d_in[5];
  const float* bv = (const float*)d_in[6];
  float* out = (float*)d_out;

  u16* Qb  = (u16*)d_ws;                               // [B*CUT*64] (pre-scaled)
  u16* W3F = Qb + (size_t)BB * CUT * HD;               // [384*512]  frag-ordered W
  u16* KF  = W3F + (size_t)384 * 512;                  // [B*64*8*512] frag-ordered K
  u16* VF  = KF + (size_t)BB * 64 * 8 * 512;           // [B*64*8*512] frag-ordered V

  wtrans_k<<<768, 256, 0, stream>>>(Wk, Wv, Wq, W3F);
  proj_k<<<512, 256, 0, stream>>>(x, W3F, bk, bv, bq, KF, VF, Qb);
  attn_k<<<512, 512, 0, stream>>>(Qb, KF, VF, out);
}

// Round 8
// 50.151 us; speedup vs baseline: 2.5434x; 1.0431x over previous
//
#include <hip/hip_runtime.h>

#define BB 4
#define TT 4096
#define CUT 2048
#define CE 1024
#define HD 64
#define QSC 0.045084220027780106f   // 1024^-0.5 * log2(e)

typedef unsigned short u16;
typedef unsigned int u32;
typedef __attribute__((ext_vector_type(8))) short bf16x8;
typedef __attribute__((ext_vector_type(4))) float f32x4;

__device__ __forceinline__ u16 f2b(float f) {
  union { float f; unsigned u; } v; v.f = f;
  unsigned r = v.u + 0x7fffu + ((v.u >> 16) & 1u);   // RNE to bf16
  return (u16)(r >> 16);
}

__device__ __forceinline__ u32 cvtpk(float lo, float hi) {
  u32 r;
  asm("v_cvt_pk_bf16_f32 %0, %1, %2" : "=v"(r) : "v"(lo), "v"(hi));
  return r;
}

// async global->LDS: per-lane 16B from g+lane*16, written to ldsbase+lane*16
__device__ __forceinline__ void gld16(const u16* g, u16* l) {
  __builtin_amdgcn_global_load_lds((const __attribute__((address_space(1))) u32*)g,
                                   (__attribute__((address_space(3))) u32*)l, 16, 0, 0);
}

// ---- Kernel 1: W3F = W in MFMA B-fragment order (contiguous 1KB wave frags) ----
__global__ void wtrans_k(const float* __restrict__ Wk, const float* __restrict__ Wv,
                         const float* __restrict__ Wq, u16* __restrict__ w3f) {
  int id = blockIdx.x * 256 + threadIdx.x;     // 196608 total
  int j    = id & 7;
  int lane = (id >> 3) & 63;
  int f    = id >> 9;                          // 0..383
  int kstep = f & 31;
  int mnt   = f >> 5;
  int m  = mnt >> 2;
  int nt = mnt & 3;
  int k   = kstep * 32 + (lane >> 4) * 8 + j;
  int col = nt * 16 + (lane & 15);
  const float* W = (m == 0) ? Wk : (m == 1) ? Wv : Wq;
  w3f[id] = f2b(W[k * 64 + col]);
}

// ---- Kernel 2: QKV projection, W staged through LDS via global_load_lds. ----
// Block: 4 waves = 2 row-groups(16 rows) x 2 K-halves(512). Double-buffered
// 24KB/iter staging (6 async frag loads per wave), T3-minimum schedule.
__launch_bounds__(256, 2)
__global__ void proj_k(const float* __restrict__ x, const u16* __restrict__ w3f,
                       const float* __restrict__ bk, const float* __restrict__ bv,
                       const float* __restrict__ bq,
                       u16* __restrict__ KF, u16* __restrict__ VF, u16* __restrict__ Qb) {
  __shared__ u16  st[2][2][12][512];            // [buf][half][mnt][frag] 48KB
  __shared__ f32x4 cl[2][12][64];               // K-combine 24KB
  const int tid  = threadIdx.x;
  const int lane = tid & 63;
  const int wv   = tid >> 6;                    // 0..3
  const int rg   = wv & 1;                      // row-group (16 rows)
  const int kh   = wv >> 1;                     // K-half
  const int l15  = lane & 15;
  const int g    = lane >> 4;
  const int r0   = blockIdx.x * 32;

  f32x4 acc[12];
  #pragma unroll
  for (int t = 0; t < 12; ++t) acc[t] = (f32x4){0.f, 0.f, 0.f, 0.f};

  const float* xrow = x + (size_t)(r0 + rg * 16 + l15) * CE + kh * 512;

  // staging: wave stages frags j = wv*6 .. wv*6+5;  h=j/12, mnt=j%12
  #define STAGE(buf, t)                                                        \
    {                                                                          \
      _Pragma("unroll")                                                        \
      for (int i = 0; i < 6; ++i) {                                            \
        int jj = wv * 6 + i;                                                   \
        int hh = jj / 12, mm = jj % 12;                                        \
        gld16(&w3f[(size_t)(mm * 32 + hh * 16 + (t)) * 512 + lane * 8],        \
              &st[buf][hh][mm][0]);                                            \
      }                                                                        \
    }

  f32x4 xs[2][2];
  xs[0][0] = *(const f32x4*)(xrow + g * 8);
  xs[0][1] = *(const f32x4*)(xrow + g * 8 + 4);
  STAGE(0, 0);
  asm volatile("s_waitcnt vmcnt(0)" ::: "memory");
  __syncthreads();

  #pragma unroll
  for (int t = 0; t < 16; ++t) {
    const int cur = t & 1, nxt = cur ^ 1;
    if (t < 15) {
      STAGE(nxt, t + 1);
      const float* xp = xrow + (t + 1) * 32 + g * 8;
      xs[nxt][0] = *(const f32x4*)xp;
      xs[nxt][1] = *(const f32x4*)(xp + 4);
    }
    bf16x8 a;
    #pragma unroll
    for (int j = 0; j < 4; ++j) {
      a[j]     = (short)f2b(xs[cur][0][j]);
      a[j + 4] = (short)f2b(xs[cur][1][j]);
    }
    #pragma unroll
    for (int mnt = 0; mnt < 12; ++mnt) {
      bf16x8 bfr = *(const bf16x8*)&st[cur][kh][mnt][lane * 8];
      acc[mnt] = __builtin_amdgcn_mfma_f32_16x16x32_bf16(a, bfr, acc[mnt], 0, 0, 0);
    }
    asm volatile("s_waitcnt vmcnt(0)" ::: "memory");
    __syncthreads();
  }
  #undef STAGE

  // ---- K-half combine ----
  if (kh == 1) {
    #pragma unroll
    for (int t = 0; t < 12; ++t) cl[rg][t][lane] = acc[t];
  }
  __syncthreads();
  if (kh == 0) {
    #pragma unroll
    for (int t = 0; t < 12; ++t) acc[t] += cl[rg][t][lane];

    const int b    = r0 >> 12;
    const int cch  = (r0 >> 6) & 63;
    const int half = (r0 >> 5) & 1;
    const int h    = rg;

    // ---- Q: row-major, pre-scaled ----
    const int t0 = r0 & (TT - 1);
    if (t0 >= CUT) {
      const int trow = t0 - CUT + h * 16;
      #pragma unroll
      for (int nt = 0; nt < 4; ++nt) {
        int col = nt * 16 + l15;
        float bc = bq[col];
        #pragma unroll
        for (int r = 0; r < 4; ++r)
          Qb[((size_t)b * CUT + trow + g * 4 + r) * HD + col] =
              f2b((acc[8 + nt][r] + bc) * QSC);
      }
    }
    // ---- K-frags ----
    {
      u16* KFc = KF + ((size_t)(b * 64 + cch) * 8) * 512;
      const int kt2 = (half * 2 + h) * 2;
      #pragma unroll
      for (int nt = 0; nt < 4; ++nt) {
        int col = nt * 16 + l15;
        float bc = bk[col];
        f32x4 v = acc[nt];
        const int off = (kt2 + (nt >> 1)) * 512 + 128 * ((nt & 1) * 2 + (l15 >> 3)) + (l15 & 7);
        #pragma unroll
        for (int r = 0; r < 4; ++r)
          KFc[off + (g * 4 + r) * 8] = f2b(v[r] + bc);
      }
    }
    // ---- V-frags ----
    {
      u16* VFc = VF + ((size_t)(b * 64 + cch) * 8) * 512;
      #pragma unroll
      for (int nt = 0; nt < 4; ++nt) {
        int col = nt * 16 + l15;
        float bc = bv[col];
        f32x4 v = acc[4 + nt];
        #pragma unroll
        for (int r = 0; r < 4; ++r) {
          int tt = h * 16 + g * 4 + r;
          VFc[(half * 4 + nt) * 512 + (l15 + 16 * (tt >> 3)) * 8 + (tt & 7)] = f2b(v[r] + bc);
        }
      }
    }
  }
}

// ---- Kernel 3: attention (UNCHANGED for clean attribution) ----
__launch_bounds__(512, 4)
__global__ void attn_k(const u16* __restrict__ Qb, const u16* __restrict__ KF,
                       const u16* __restrict__ VF, float* __restrict__ out) {
  __shared__ u32   PLd[8][16][36];              // per-wave P (bf16 pairs): [q][key/2]
  __shared__ float OO[8][16][66];               // per-wave unnormalized O: [q][d]
  __shared__ float OL[8][16];                   // per-wave l-sum per q
  const int tid  = threadIdx.x;
  const int lane = tid & 63;
  const int wv   = tid >> 6;
  const int l15  = lane & 15;
  const int g    = lane >> 4;
  const int id   = blockIdx.x;                  // 0..511
  const int b    = id & 3;
  const int i0   = (id >> 2) * 16;

  const int qabs = CUT + i0 + l15;              // abs pos of this lane's q column (S^T)
  const int qmin = CUT + i0;

  const u16* qrow = Qb + ((size_t)b * CUT + i0 + l15) * HD;
  bf16x8 qf0 = *(const bf16x8*)&qrow[g * 8];
  bf16x8 qf1 = *(const bf16x8*)&qrow[32 + g * 8];

  f32x4 o[4];
  #pragma unroll
  for (int dt = 0; dt < 4; ++dt) o[dt] = (f32x4){0.f, 0.f, 0.f, 0.f};
  float lsum = 0.f;

  const int kv_end = CUT + i0 + 16;
  const int nch = (kv_end + 63) >> 6;           // 33..64 chunks
  const u16* KFb = KF + (size_t)b * 64 * 8 * 512;
  const u16* VFb = VF + (size_t)b * 64 * 8 * 512;

  for (int c = wv; c < nch; c += 8) {
    const int kv0 = c << 6;

    const u16* kp = KFb + (size_t)c * 4096 + lane * 8;
    bf16x8 ka[4][2];
    #pragma unroll
    for (int kt = 0; kt < 4; ++kt) {
      ka[kt][0] = *(const bf16x8*)(kp + (kt * 2 + 0) * 512);
      ka[kt][1] = *(const bf16x8*)(kp + (kt * 2 + 1) * 512);
    }
    const u16* vp = VFb + (size_t)c * 4096 + lane * 8;
    bf16x8 va[2][4];
    #pragma unroll
    for (int c2 = 0; c2 < 2; ++c2)
      #pragma unroll
      for (int dt = 0; dt < 4; ++dt)
        va[c2][dt] = *(const bf16x8*)(vp + (c2 * 4 + dt) * 512);

    f32x4 st[4];
    __builtin_amdgcn_s_setprio(1);
    #pragma unroll
    for (int kt = 0; kt < 4; ++kt) {
      f32x4 s = (f32x4){0.f, 0.f, 0.f, 0.f};
      s = __builtin_amdgcn_mfma_f32_16x16x32_bf16(ka[kt][0], qf0, s, 0, 0, 0);
      s = __builtin_amdgcn_mfma_f32_16x16x32_bf16(ka[kt][1], qf1, s, 0, 0, 0);
      st[kt] = s;
    }
    __builtin_amdgcn_s_setprio(0);

    if (kv0 + 63 <= qmin) {                     // wave-uniform: fully unmasked chunk
      #pragma unroll
      for (int kt = 0; kt < 4; ++kt)
        #pragma unroll
        for (int r = 0; r < 4; ++r) {
          float p = exp2f(st[kt][r]);
          st[kt][r] = p;
          lsum += p;
        }
    } else {
      #pragma unroll
      for (int kt = 0; kt < 4; ++kt)
        #pragma unroll
        for (int r = 0; r < 4; ++r) {
          int key = kv0 + kt * 16 + g * 4 + r;
          float p = exp2f(st[kt][r]);
          p = (key <= qabs) ? p : 0.f;
          st[kt][r] = p;
          lsum += p;
        }
    }

    #pragma unroll
    for (int kt = 0; kt < 4; ++kt) {            // pack P->bf16, wave-private LDS
      u32 d0 = cvtpk(st[kt][0], st[kt][1]);
      u32 d1 = cvtpk(st[kt][2], st[kt][3]);
      u32* p = &PLd[wv][l15][kt * 8 + g * 2];
      p[0] = d0; p[1] = d1;
    }

    __builtin_amdgcn_s_setprio(1);
    #pragma unroll
    for (int c2 = 0; c2 < 2; ++c2) {
      bf16x8 pa = *(const bf16x8*)&PLd[wv][l15][c2 * 16 + g * 4];
      #pragma unroll
      for (int dt = 0; dt < 4; ++dt)
        o[dt] = __builtin_amdgcn_mfma_f32_16x16x32_bf16(pa, va[c2][dt], o[dt], 0, 0, 0);
    }
    __builtin_amdgcn_s_setprio(0);
  }

  lsum += __shfl_xor(lsum, 16);
  lsum += __shfl_xor(lsum, 32);
  if (lane < 16) OL[wv][l15] = lsum;
  #pragma unroll
  for (int dt = 0; dt < 4; ++dt)
    #pragma unroll
    for (int r = 0; r < 4; ++r)
      OO[wv][g * 4 + r][dt * 16 + l15] = o[dt][r];
  __syncthreads();

  #pragma unroll
  for (int e = tid; e < 1024; e += 512) {
    int q = e >> 6, d = e & 63;
    float L = 0.f, O = 0.f;
    #pragma unroll
    for (int w = 0; w < 8; ++w) { L += OL[w][q]; O += OO[w][q][d]; }
    out[((size_t)b * CUT + i0 + q) * HD + d] = O / L;
  }
}

extern "C" void kernel_launch(void* const* d_in, const int* in_sizes, int n_in,
                              void* d_out, int out_size, void* d_ws, size_t ws_size,
                              hipStream_t stream) {
  const float* x  = (const float*)d_in[0];
  const float* Wq = (const float*)d_in[1];
  const float* bq = (const float*)d_in[2];
  const float* Wk = (const float*)d_in[3];
  const float* bk = (const float*)d_in[4];
  const float* Wv = (const float*)d_in[5];
  const float* bv = (const float*)d_in[6];
  float* out = (float*)d_out;

  u16* Qb  = (u16*)d_ws;                               // [B*CUT*64] (pre-scaled)
  u16* W3F = Qb + (size_t)BB * CUT * HD;               // [384*512]  frag-ordered W
  u16* KF  = W3F + (size_t)384 * 512;                  // [B*64*8*512] frag-ordered K
  u16* VF  = KF + (size_t)BB * 64 * 8 * 512;           // [B*64*8*512] frag-ordered V

  wtrans_k<<<768, 256, 0, stream>>>(Wk, Wv, Wq, W3F);
  proj_k<<<512, 256, 0, stream>>>(x, W3F, bk, bv, bq, KF, VF, Qb);
  attn_k<<<512, 512, 0, stream>>>(Qb, KF, VF, out);
}